// Round 1
// baseline (210.471 us; speedup 1.0000x reference)
//
#include <hip/hip_runtime.h>
#include <cstdint>

// BinConv2dEval: y = conv3x3(x,W) + bias; out = (sign*y >= 0) ? 1 : 0
// x: [32][128][64][64] fp32 in {0,1};  W: [256][128][3][3] fp32 in {-1,0,1}
// bias: [256] integer-valued fp32; sign: [256] in {-1,+1}; out fp32 NCHW.
//
// R13 baseline: 206.2 us total (fused ~58 us). Phase C (MX-FP4 GEMM via
// mfma_scale_f32_32x32x64_f8f6f4, chunk-swizzled pixel blocks, direct NT
// epilogue) is verified and unchanged here.
// R15 (this round):
//   - XCD-chunked block swizzle: logical=(bx&7)*128+(bx>>3); each XCD owns
//     4 complete images -> strip-neighbor row re-reads hit per-XCD L2.
//   - Phase A spread over all 512 threads (8 uint4-pairs each, was 256x16).
//     LDS write banks (17*pr + 8*qh) mod 32 -> <=2-way (free).
//   - Phase B rewritten: v_perm_b32 4x4-byte transpose. 16 aligned
//     ds_read_b32 + 32 v_perm per item replaces 64 ds_read_u8 + or/shift.
//     Read banks (16c + pq + 17*row) mod 32 -> <=2-way. Write pattern
//     (chunk-swizzled b128, verified conflict-free in R11) preserved.
//  ws: wq4 = fp4 fragment-major [tap(9)][co32(8)][s(2)][lane(64)x16B] (144 KB)

#define NIMG 32
#define CIN  128
#define HH   64
#define WW   64
#define COUT 256
#define X4ROW   4224                  // 66 px * 64 B
#define STG_SY  4352                  // 64 cipair * 68 B
#define STG_BYTES (4 * STG_SY)        // 17408
#define LDS_TOTAL (STG_BYTES + 4 * X4ROW)   // 34304
#define WQ4_BYTES ((size_t)9 * 8 * 2 * 64 * 16)   // 147456

typedef int   v4i  __attribute__((ext_vector_type(4)));
typedef int   v8i  __attribute__((ext_vector_type(8)));
typedef float v16f __attribute__((ext_vector_type(16)));

// -------------------------------------------------------------------------
// Weight prepack: OIHW fp32 -> fp4 fragment-major wq4 (verified R11-R13).
// byte b of a fragment = ci pair (2b even -> low nibble, 2b+1 -> high).
__global__ __launch_bounds__(256) void w_prepack(const float* __restrict__ w,
                                                 int8_t* __restrict__ wq4) {
    const int idx = blockIdx.x * 256 + threadIdx.x;   // 0..147455
    if (idx >= (int)WQ4_BYTES) return;
    const int b    = idx & 15;
    const int lane = (idx >> 4) & 63;
    const int s    = (idx >> 10) & 1;
    const int co32 = (idx >> 11) & 7;
    const int tap  = idx >> 14;             // 0..8
    const int co   = co32 * 32 + (lane & 31);
    const int ci0  = s * 64 + (lane >> 5) * 32 + b * 2;
    const int i0 = (int)w[(size_t)(co * CIN + ci0) * 9 + tap];
    const int i1 = (int)w[(size_t)(co * CIN + ci0 + 1) * 9 + tap];
    const uint32_t n0 = (i0 == 0) ? 0u : ((i0 > 0) ? 0x2u : 0xAu);
    const uint32_t n1 = (i1 == 0) ? 0u : ((i1 > 0) ? 0x2u : 0xAu);
    wq4[idx] = (int8_t)(n0 | (n1 << 4));
}

__device__ __forceinline__ v8i widen(v4i x) {
    v8i r = {x[0], x[1], x[2], x[3], 0, 0, 0, 0};   // fp4 uses low 4 regs
    return r;
}

// -------------------------------------------------------------------------
// Fused kernel. grid 1024 = n(32) x ystrip(32); block 512 = 8 waves.
__global__ __launch_bounds__(512) void binconv_fused(
    const float* __restrict__ x, const int8_t* __restrict__ wq4,
    const float* __restrict__ bias, const float* __restrict__ sign,
    float* __restrict__ out) {

    __shared__ __align__(16) int8_t Smem[LDS_TOTAL];
    int8_t* Stg = Smem;                 // [4 sy][64 cipair][68] nibble-pair bytes
    int8_t* X4  = Smem + STG_BYTES;     // [4 sy][66 px][64 B] fp4 swizzled

    const int t      = threadIdx.x;
    const int bx_raw = blockIdx.x;
    // XCD-chunked bijective swizzle: 1024 wg / 8 XCD = 128 per XCD.
    // XCD k gets logical blocks [128k, 128k+128) = images 4k..4k+3, all strips.
    const int bx = ((bx_raw & 7) << 7) | (bx_raw >> 3);
    const int n  = bx >> 5;
    const int y0 = (bx & 31) << 1;      // 2 output rows per block

    // ---- Phase A: x -> nibble-pair bytes in staging (ALL 512 threads) ----
    {
        const int sy = t >> 7;          // strip row 0..3
        const int pr = (t >> 1) & 63;   // ci pair
        const int qh = t & 1;           // q half: 0 -> q 0..7, 1 -> q 8..15
        const int y  = y0 + sy - 1;
        uint32_t* sp = (uint32_t*)(Stg + sy * STG_SY + pr * 68) + qh * 8;
        if (y >= 0 && y < HH) {
            const uint4* r0 =
                (const uint4*)(x + (((size_t)n * CIN + 2 * pr)     * HH + y) * WW) + qh * 8;
            const uint4* r1 =
                (const uint4*)(x + (((size_t)n * CIN + 2 * pr + 1) * HH + y) * WW) + qh * 8;
#pragma unroll
            for (int q = 0; q < 8; ++q) {
                const uint4 a = r0[q], b = r1[q];
                // byte i = fp4(even ci) | fp4(odd ci)<<4 ; 1.0f has bits 28,29 set
                uint32_t wd = ((a.x >> 28) & 0x2u)        | ((b.x >> 24) & 0x20u)
                            | ((a.y >> 20) & 0x200u)      | ((b.y >> 16) & 0x2000u)
                            | ((a.z >> 12) & 0x20000u)    | ((b.z >> 8) & 0x200000u)
                            | ((a.w >> 4)  & 0x2000000u)  | ( b.w       & 0x20000000u);
                sp[q] = wd;
            }
        } else {
#pragma unroll
            for (int q = 0; q < 8; ++q) sp[q] = 0u;
        }
    }
    __syncthreads();

    // ---- Phase B: transpose -> swizzled fp4 pixel blocks (v_perm 4x4) ----
    // Item (sy, pq, c): pixel quad pxp0..pxp0+3, output chunk c (wrd[4c..4c+3]).
    // For u=0..3: read 4 aligned dwords from rows 16c+4u+j -> 4x4 byte
    // transpose via 8 v_perm -> dword u of each pixel's chunk-c int4.
    if (t < 288) {
        if (t < 256) {
            const int c    = t & 3;
            const int pq   = (t >> 2) & 15;
            const int sy   = t >> 6;
            const int pxp0 = 1 + 4 * pq;
            const uint32_t* srow = (const uint32_t*)(Stg + sy * STG_SY); // 17 dw/row
            v4i val[4];                 // val[p][u] = wrd[4c+u] for pixel pxp0+p
#pragma unroll
            for (int u = 0; u < 4; ++u) {
                const int r0 = 16 * c + 4 * u;
                const uint32_t S0 = srow[(r0 + 0) * 17 + pq];
                const uint32_t S1 = srow[(r0 + 1) * 17 + pq];
                const uint32_t S2 = srow[(r0 + 2) * 17 + pq];
                const uint32_t S3 = srow[(r0 + 3) * 17 + pq];
                // M0=[S0_0,S1_0,S0_1,S1_1] M1=[S0_2,S1_2,S0_3,S1_3] (le bytes)
                const uint32_t M0 = __builtin_amdgcn_perm(S0, S1, 0x01050004u);
                const uint32_t M1 = __builtin_amdgcn_perm(S0, S1, 0x03070206u);
                const uint32_t M2 = __builtin_amdgcn_perm(S2, S3, 0x01050004u);
                const uint32_t M3 = __builtin_amdgcn_perm(S2, S3, 0x03070206u);
                // X_p = [S0_p,S1_p,S2_p,S3_p]
                const uint32_t X0 = __builtin_amdgcn_perm(M2, M0, 0x05040100u);
                const uint32_t X1 = __builtin_amdgcn_perm(M2, M0, 0x07060302u);
                const uint32_t X2 = __builtin_amdgcn_perm(M3, M1, 0x05040100u);
                const uint32_t X3 = __builtin_amdgcn_perm(M3, M1, 0x07060302u);
                val[0][u] = (int)X0; val[1][u] = (int)X1;
                val[2][u] = (int)X2; val[3][u] = (int)X3;
            }
            int8_t* dsty = X4 + sy * X4ROW;
#pragma unroll
            for (int p = 0; p < 4; ++p) {
                const int pxp = pxp0 + p;
                *(v4i*)(dsty + pxp * 64 + ((c ^ (pxp & 3)) << 4)) = val[p];
            }
        } else {
            // zero padding pixels pxp = 0 and 65 (all chunks; swizzle moot)
            const int u2   = t - 256;   // 0..31
            const int c    = u2 & 3;
            const int side = (u2 >> 2) & 1;
            const int sy   = u2 >> 3;
            const v4i z = {0, 0, 0, 0};
            *(v4i*)(X4 + sy * X4ROW + (side ? 65 : 0) * 64 + (c << 4)) = z;
        }
    }
    __syncthreads();

    // ---- Phase C: GEMM (verified R11/R12 structure, unchanged) ----
    const int wid  = t >> 6;            // 0..7
    const int lane = t & 63;
    const int m_lo = lane & 31;         // D col (m); A co row
    const int hi   = lane >> 5;         // k-half
    const int co_off = (wid >> 1) * 64; // 0,64,128,192
    const int yw     = wid & 1;         // output row y0 / y0+1
    const int ct0    = co_off >> 5;     // first co32 tile

    const int8_t* Xw  = X4 + yw * X4ROW;
    const int8_t* wqb = wq4 + lane * 16;

    v16f acc[2][2] = {};                // [ct][mt], fp32 exact

#pragma unroll
    for (int tap = 0; tap < 9; ++tap) {
        const int ky = tap / 3, kx = tap % 3;
        const int8_t* xl = Xw + ky * X4ROW;
        const int px0 = m_lo + kx;
        const int pk  = px0 & 3;

        v4i af[2][2];                   // [ct][s]
#pragma unroll
        for (int c = 0; c < 2; ++c)
#pragma unroll
            for (int s = 0; s < 2; ++s)
                af[c][s] = *(const v4i*)(wqb
                    + ((((tap * 8 + ct0 + c) * 2) + s) << 10));

        v4i bf[2][2];                   // [mt][s]
#pragma unroll
        for (int s = 0; s < 2; ++s) {
            const int sw = (((s << 1) + hi) ^ pk) << 4;
#pragma unroll
            for (int m = 0; m < 2; ++m)
                bf[m][s] = *(const v4i*)(xl + (px0 + m * 32) * 64 + sw);
        }
#pragma unroll
        for (int s = 0; s < 2; ++s)
#pragma unroll
            for (int c = 0; c < 2; ++c)
#pragma unroll
                for (int m = 0; m < 2; ++m)
                    acc[c][m] = __builtin_amdgcn_mfma_scale_f32_32x32x64_f8f6f4(
                        widen(af[c][s]), widen(bf[m][s]), acc[c][m],
                        4, 4,             // cbsz=fp4, blgp=fp4
                        0, 0x7F7F7F7F,    // scale_a = 2^0
                        0, 0x7F7F7F7F);   // scale_b = 2^0
    }

    // ---- epilogue: direct NT dword stores from acc (no LDS round-trip).
    // D 32x32 layout: col(m) = lane&31, row(co) = (r&3)+8*(r>>2)+4*hi.
    const float* bco = bias + co_off;
    const float* sco = sign + co_off;
    float* outb = out + ((size_t)n * COUT + co_off) * (HH * WW)
                + (y0 + yw) * WW + m_lo;
#pragma unroll
    for (int c = 0; c < 2; ++c) {
#pragma unroll
        for (int r = 0; r < 16; ++r) {
            const int co_l = c * 32 + (r & 3) + 8 * (r >> 2) + 4 * hi;
            const float bv = bco[co_l];
            const float sv = sco[co_l];
            float* orow = outb + (size_t)co_l * (HH * WW);
#pragma unroll
            for (int m = 0; m < 2; ++m) {
                const float yv = acc[c][m][r] + bv;     // exact integer
                const bool on = (sv > 0.0f) ? (yv >= 0.0f) : (yv <= 0.0f);
                __builtin_nontemporal_store(on ? 1.0f : 0.0f, orow + m * 32);
            }
        }
    }
}

// -------------------------------------------------------------------------
// Fallback (only if ws too small): naive direct conv.
__global__ __launch_bounds__(256) void naive_conv(
    const float* __restrict__ x, const float* __restrict__ w,
    const float* __restrict__ bias, const float* __restrict__ sign,
    float* __restrict__ out) {
    const int idx = blockIdx.x * 256 + threadIdx.x;
    const int xc = idx & 63, y = (idx >> 6) & 63, co = (idx >> 12) & 255,
              n = idx >> 20;
    float s = 0.f;
    for (int ci = 0; ci < CIN; ++ci)
        for (int ky = 0; ky < 3; ++ky) {
            const int iy = y + ky - 1;
            if (iy < 0 || iy >= HH) continue;
            for (int kx = 0; kx < 3; ++kx) {
                const int ix = xc + kx - 1;
                if (ix < 0 || ix >= WW) continue;
                s += x[((size_t)(n * CIN + ci) * HH + iy) * WW + ix] *
                     w[((size_t)(co * CIN + ci) * 3 + ky) * 3 + kx];
            }
        }
    const float yv = s + bias[co];
    out[idx] = ((sign[co] > 0.f) ? (yv >= 0.f) : (yv <= 0.f)) ? 1.0f : 0.0f;
}

// -------------------------------------------------------------------------
extern "C" void kernel_launch(void* const* d_in, const int* in_sizes, int n_in,
                              void* d_out, int out_size, void* d_ws, size_t ws_size,
                              hipStream_t stream) {
    const float* x    = (const float*)d_in[0];
    const float* w    = (const float*)d_in[1];
    const float* bias = (const float*)d_in[2];
    const float* sign = (const float*)d_in[3];
    float* out = (float*)d_out;

    if (ws_size < WQ4_BYTES) {
        naive_conv<<<dim3((NIMG * COUT * HH * WW) / 256), 256, 0, stream>>>(
            x, w, bias, sign, out);
        return;
    }
    int8_t* wq4 = (int8_t*)d_ws;

    w_prepack<<<dim3((int)((WQ4_BYTES + 255) / 256)), 256, 0, stream>>>(w, wq4);
    binconv_fused<<<dim3(NIMG * (HH / 2)), 512, 0, stream>>>(
        x, wq4, bias, sign, out);
}

// Round 2
// 206.138 us; speedup vs baseline: 1.0210x; 1.0210x over previous
//
#include <hip/hip_runtime.h>
#include <cstdint>

// BinConv2dEval: y = conv3x3(x,W) + bias; out = (sign*y >= 0) ? 1 : 0
// x: [32][128][64][64] fp32 in {0,1};  W: [256][128][3][3] fp32 in {-1,0,1}
// bias: [256] integer-valued fp32; sign: [256] in {-1,+1}; out fp32 NCHW.
//
// FINAL = R13 (best measured: 206.2 us total; fused kernel ~40-44 us).
// R11: MX-FP4 GEMM via mfma_scale_f32_32x32x64_f8f6f4 (exact fp32 accum),
//      chunk-swizzled pixel blocks (0 LDS bank conflicts, verified).
// R12: fused per-block LDS build of the fp4 X-strip (no prepass kernel,
//      no xt round-trip). R13: pair-packed Phase A + direct NT epilogue.
// R14 (1024-thr, 4-row strips) regressed -> reverted.
// R15 (XCD-chunked swizzle + 512-thr Phase A + v_perm Phase B) regressed
//      kernel portion ~43.6 -> ~53.3 us (fill-decomposed) -> reverted.
//      x is LLC-resident; swizzle had no HBM re-fetch to save (m160 case).
//  ws: wq4 = fp4 fragment-major [tap(9)][co32(8)][s(2)][lane(64)x16B] (144 KB)

#define NIMG 32
#define CIN  128
#define HH   64
#define WW   64
#define COUT 256
#define X4ROW   4224                  // 66 px * 64 B
#define STG_SY  4352                  // 64 cipair * 68 B
#define STG_BYTES (4 * STG_SY)        // 17408
#define LDS_TOTAL (STG_BYTES + 4 * X4ROW)   // 34304
#define WQ4_BYTES ((size_t)9 * 8 * 2 * 64 * 16)   // 147456

typedef int   v4i  __attribute__((ext_vector_type(4)));
typedef int   v8i  __attribute__((ext_vector_type(8)));
typedef float v16f __attribute__((ext_vector_type(16)));

// -------------------------------------------------------------------------
// Weight prepack: OIHW fp32 -> fp4 fragment-major wq4 (verified R11-R13).
// byte b of a fragment = ci pair (2b even -> low nibble, 2b+1 -> high).
__global__ __launch_bounds__(256) void w_prepack(const float* __restrict__ w,
                                                 int8_t* __restrict__ wq4) {
    const int idx = blockIdx.x * 256 + threadIdx.x;   // 0..147455
    if (idx >= (int)WQ4_BYTES) return;
    const int b    = idx & 15;
    const int lane = (idx >> 4) & 63;
    const int s    = (idx >> 10) & 1;
    const int co32 = (idx >> 11) & 7;
    const int tap  = idx >> 14;             // 0..8
    const int co   = co32 * 32 + (lane & 31);
    const int ci0  = s * 64 + (lane >> 5) * 32 + b * 2;
    const int i0 = (int)w[(size_t)(co * CIN + ci0) * 9 + tap];
    const int i1 = (int)w[(size_t)(co * CIN + ci0 + 1) * 9 + tap];
    const uint32_t n0 = (i0 == 0) ? 0u : ((i0 > 0) ? 0x2u : 0xAu);
    const uint32_t n1 = (i1 == 0) ? 0u : ((i1 > 0) ? 0x2u : 0xAu);
    wq4[idx] = (int8_t)(n0 | (n1 << 4));
}

__device__ __forceinline__ v8i widen(v4i x) {
    v8i r = {x[0], x[1], x[2], x[3], 0, 0, 0, 0};   // fp4 uses low 4 regs
    return r;
}

// -------------------------------------------------------------------------
// Fused kernel. grid 1024 = n(32) x ystrip(32); block 512 = 8 waves.
__global__ __launch_bounds__(512) void binconv_fused(
    const float* __restrict__ x, const int8_t* __restrict__ wq4,
    const float* __restrict__ bias, const float* __restrict__ sign,
    float* __restrict__ out) {

    __shared__ __align__(16) int8_t Smem[LDS_TOTAL];
    int8_t* Stg = Smem;                 // [4 sy][64 cipair][68] nibble-pair bytes
    int8_t* X4  = Smem + STG_BYTES;     // [4 sy][66 px][64 B] fp4 swizzled

    const int t  = threadIdx.x;
    const int bx = blockIdx.x;
    const int n  = bx >> 5;
    const int y0 = (bx & 31) << 1;      // 2 output rows per block

    // ---- Phase A: x -> nibble-pair bytes in staging (256 threads) ----
    if (t < 256) {
        const int sy = t >> 6;          // strip row 0..3
        const int pr = t & 63;          // ci pair
        const int y  = y0 + sy - 1;
        uint32_t* sp = (uint32_t*)(Stg + sy * STG_SY + pr * 68);
        if (y >= 0 && y < HH) {
            const uint4* r0 =
                (const uint4*)(x + (((size_t)n * CIN + 2 * pr)     * HH + y) * WW);
            const uint4* r1 =
                (const uint4*)(x + (((size_t)n * CIN + 2 * pr + 1) * HH + y) * WW);
#pragma unroll
            for (int q = 0; q < 16; ++q) {
                const uint4 a = r0[q], b = r1[q];
                // byte i = fp4(even ci) | fp4(odd ci)<<4 ; 1.0f has bits 28,29 set
                uint32_t wd = ((a.x >> 28) & 0x2u)        | ((b.x >> 24) & 0x20u)
                            | ((a.y >> 20) & 0x200u)      | ((b.y >> 16) & 0x2000u)
                            | ((a.z >> 12) & 0x20000u)    | ((b.z >> 8) & 0x200000u)
                            | ((a.w >> 4)  & 0x2000000u)  | ( b.w       & 0x20000000u);
                sp[q] = wd;
            }
        } else {
#pragma unroll
            for (int q = 0; q < 16; ++q) sp[q] = 0u;
        }
    }
    __syncthreads();

    // ---- Phase B: transpose -> swizzled fp4 pixel blocks (264 threads) ----
    if (t < 264) {
        const int sy  = t / 66;
        const int pxp = t - sy * 66;    // padded pixel 0..65
        int8_t* dst = X4 + sy * X4ROW + pxp * 64;
        if (pxp == 0 || pxp == 65) {
            const int4 z = {0, 0, 0, 0};
#pragma unroll
            for (int c = 0; c < 4; ++c) *(int4*)(dst + c * 16) = z;
        } else {
            const int8_t* src = Stg + sy * STG_SY + (pxp - 1);
            uint32_t wrd[16];
#pragma unroll
            for (int k = 0; k < 16; ++k) {
                const uint32_t b0 = (uint8_t)src[(4 * k + 0) * 68];
                const uint32_t b1 = (uint8_t)src[(4 * k + 1) * 68];
                const uint32_t b2 = (uint8_t)src[(4 * k + 2) * 68];
                const uint32_t b3 = (uint8_t)src[(4 * k + 3) * 68];
                wrd[k] = b0 | (b1 << 8) | (b2 << 16) | (b3 << 24);
            }
            const int sk = pxp & 3;     // chunk swizzle key (verified pattern)
#pragma unroll
            for (int c = 0; c < 4; ++c) {
                int4 vv = {(int)wrd[c*4], (int)wrd[c*4+1],
                           (int)wrd[c*4+2], (int)wrd[c*4+3]};
                *(int4*)(dst + ((c ^ sk) << 4)) = vv;
            }
        }
    }
    __syncthreads();

    // ---- Phase C: GEMM (verified R11/R12 structure) ----
    const int wid  = t >> 6;            // 0..7
    const int lane = t & 63;
    const int m_lo = lane & 31;         // D col (m); A co row
    const int hi   = lane >> 5;         // k-half
    const int co_off = (wid >> 1) * 64; // 0,64,128,192
    const int yw     = wid & 1;         // output row y0 / y0+1
    const int ct0    = co_off >> 5;     // first co32 tile

    const int8_t* Xw  = X4 + yw * X4ROW;
    const int8_t* wqb = wq4 + lane * 16;

    v16f acc[2][2] = {};                // [ct][mt], fp32 exact

#pragma unroll
    for (int tap = 0; tap < 9; ++tap) {
        const int ky = tap / 3, kx = tap % 3;
        const int8_t* xl = Xw + ky * X4ROW;
        const int px0 = m_lo + kx;
        const int pk  = px0 & 3;

        v4i af[2][2];                   // [ct][s]
#pragma unroll
        for (int c = 0; c < 2; ++c)
#pragma unroll
            for (int s = 0; s < 2; ++s)
                af[c][s] = *(const v4i*)(wqb
                    + ((((tap * 8 + ct0 + c) * 2) + s) << 10));

        v4i bf[2][2];                   // [mt][s]
#pragma unroll
        for (int s = 0; s < 2; ++s) {
            const int sw = (((s << 1) + hi) ^ pk) << 4;
#pragma unroll
            for (int m = 0; m < 2; ++m)
                bf[m][s] = *(const v4i*)(xl + (px0 + m * 32) * 64 + sw);
        }
#pragma unroll
        for (int s = 0; s < 2; ++s)
#pragma unroll
            for (int c = 0; c < 2; ++c)
#pragma unroll
                for (int m = 0; m < 2; ++m)
                    acc[c][m] = __builtin_amdgcn_mfma_scale_f32_32x32x64_f8f6f4(
                        widen(af[c][s]), widen(bf[m][s]), acc[c][m],
                        4, 4,             // cbsz=fp4, blgp=fp4
                        0, 0x7F7F7F7F,    // scale_a = 2^0
                        0, 0x7F7F7F7F);   // scale_b = 2^0
    }

    // ---- epilogue: direct NT dword stores from acc (no LDS round-trip).
    // D 32x32 layout: col(m) = lane&31, row(co) = (r&3)+8*(r>>2)+4*hi.
    const float* bco = bias + co_off;
    const float* sco = sign + co_off;
    float* outb = out + ((size_t)n * COUT + co_off) * (HH * WW)
                + (y0 + yw) * WW + m_lo;
#pragma unroll
    for (int c = 0; c < 2; ++c) {
#pragma unroll
        for (int r = 0; r < 16; ++r) {
            const int co_l = c * 32 + (r & 3) + 8 * (r >> 2) + 4 * hi;
            const float bv = bco[co_l];
            const float sv = sco[co_l];
            float* orow = outb + (size_t)co_l * (HH * WW);
#pragma unroll
            for (int m = 0; m < 2; ++m) {
                const float yv = acc[c][m][r] + bv;     // exact integer
                const bool on = (sv > 0.0f) ? (yv >= 0.0f) : (yv <= 0.0f);
                __builtin_nontemporal_store(on ? 1.0f : 0.0f, orow + m * 32);
            }
        }
    }
}

// -------------------------------------------------------------------------
// Fallback (only if ws too small): naive direct conv.
__global__ __launch_bounds__(256) void naive_conv(
    const float* __restrict__ x, const float* __restrict__ w,
    const float* __restrict__ bias, const float* __restrict__ sign,
    float* __restrict__ out) {
    const int idx = blockIdx.x * 256 + threadIdx.x;
    const int xc = idx & 63, y = (idx >> 6) & 63, co = (idx >> 12) & 255,
              n = idx >> 20;
    float s = 0.f;
    for (int ci = 0; ci < CIN; ++ci)
        for (int ky = 0; ky < 3; ++ky) {
            const int iy = y + ky - 1;
            if (iy < 0 || iy >= HH) continue;
            for (int kx = 0; kx < 3; ++kx) {
                const int ix = xc + kx - 1;
                if (ix < 0 || ix >= WW) continue;
                s += x[((size_t)(n * CIN + ci) * HH + iy) * WW + ix] *
                     w[((size_t)(co * CIN + ci) * 3 + ky) * 3 + kx];
            }
        }
    const float yv = s + bias[co];
    out[idx] = ((sign[co] > 0.f) ? (yv >= 0.f) : (yv <= 0.f)) ? 1.0f : 0.0f;
}

// -------------------------------------------------------------------------
extern "C" void kernel_launch(void* const* d_in, const int* in_sizes, int n_in,
                              void* d_out, int out_size, void* d_ws, size_t ws_size,
                              hipStream_t stream) {
    const float* x    = (const float*)d_in[0];
    const float* w    = (const float*)d_in[1];
    const float* bias = (const float*)d_in[2];
    const float* sign = (const float*)d_in[3];
    float* out = (float*)d_out;

    if (ws_size < WQ4_BYTES) {
        naive_conv<<<dim3((NIMG * COUT * HH * WW) / 256), 256, 0, stream>>>(
            x, w, bias, sign, out);
        return;
    }
    int8_t* wq4 = (int8_t*)d_ws;

    w_prepack<<<dim3((int)((WQ4_BYTES + 255) / 256)), 256, 0, stream>>>(w, wq4);
    binconv_fused<<<dim3(NIMG * (HH / 2)), 512, 0, stream>>>(
        x, wq4, bias, sign, out);
}